// Round 1
// baseline (1090.461 us; speedup 1.0000x reference)
//
#include <hip/hip_runtime.h>
#include <math.h>

// Problem dims (fixed by the reference)
constexpr int Bv = 4;
constexpr int Nv = 4096;
constexpr int Kv = 32;    // nsample
constexpr int Cv = 3;     // xyz
constexpr int Dv = 64;    // feat
constexpr int DP = 128;   // all_channel
constexpr int DC = Cv + Dv + 2;  // 69 channels of dgf
constexpr float ALPHA = 0.2f;

// ---------------------------------------------------------------------------
// Kernel 1: attention path.
// One block per (b,n). 256 threads = 4 waves.
//   e[k][c] = leaky_relu( sum_d nfn[k][d] * a[d][c] )
//   att = softmax_k(e); pooled[c] = sum_k att[k][c]*nfn[k][c]
//   out[c] = sum_d pooled[d]*w1[d][c] + b1[c]
// Thread t owns column c = t&127 and k-half kh = t>>7 (16 k's each).
// ---------------------------------------------------------------------------
__global__ __launch_bounds__(256) void attn_kernel(
    const float* __restrict__ nfn,   // [B,N,K,DP]
    const float* __restrict__ a,     // [DP,DP]
    const float* __restrict__ w1,    // [DP,DP]
    const float* __restrict__ b1,    // [DP]
    float* __restrict__ out)         // [B,N,DP]
{
    __shared__ float s_nfn[Kv][DP];      // 16 KB
    __shared__ float s_max[2][DP];
    __shared__ float s_sum[2][DP];
    __shared__ float s_pool[2][DP];

    const int bn = blockIdx.x;
    const int t  = threadIdx.x;
    const float* nfn_p = nfn + (size_t)bn * Kv * DP;

    // stage nfn[b,n] -> LDS, float4 coalesced (4096 floats / 256 thr = 4 f4 each)
    {
        const float4* src = (const float4*)nfn_p;
        float4* dst = (float4*)(&s_nfn[0][0]);
#pragma unroll
        for (int i = 0; i < 4; ++i) dst[t + 256 * i] = src[t + 256 * i];
    }
    __syncthreads();

    const int c  = t & 127;
    const int kh = t >> 7;  // 0 or 1

    float e[16];
#pragma unroll
    for (int i = 0; i < 16; ++i) e[i] = 0.f;

    // e[k][c] accumulation; a-column staged in registers 32 d's at a time
    for (int dd = 0; dd < DP; dd += 32) {
        float ac[32];
#pragma unroll
        for (int j = 0; j < 32; ++j) ac[j] = a[(size_t)(dd + j) * DP + c];
#pragma unroll
        for (int i = 0; i < 16; ++i) {
            const float4* row = (const float4*)(&s_nfn[kh * 16 + i][dd]);
#pragma unroll
            for (int j = 0; j < 8; ++j) {
                float4 v = row[j];
                e[i] = fmaf(v.x, ac[4 * j + 0], e[i]);
                e[i] = fmaf(v.y, ac[4 * j + 1], e[i]);
                e[i] = fmaf(v.z, ac[4 * j + 2], e[i]);
                e[i] = fmaf(v.w, ac[4 * j + 3], e[i]);
            }
        }
    }

    // leaky relu
#pragma unroll
    for (int i = 0; i < 16; ++i) e[i] = e[i] > 0.f ? e[i] : ALPHA * e[i];

    // partial max over own 16 k's
    float m = e[0];
#pragma unroll
    for (int i = 1; i < 16; ++i) m = fmaxf(m, e[i]);
    s_max[kh][c] = m;
    __syncthreads();
    const float mo = fmaxf(s_max[0][c], s_max[1][c]);

    // partial sum + partial pooled
    float s = 0.f, p = 0.f;
#pragma unroll
    for (int i = 0; i < 16; ++i) {
        float ex = expf(e[i] - mo);
        s += ex;
        p += ex * s_nfn[kh * 16 + i][c];
    }
    s_sum[kh][c]  = s;
    s_pool[kh][c] = p;
    __syncthreads();

    if (kh == 0) {
        s_pool[0][c] = (s_pool[0][c] + s_pool[1][c]) /
                       (s_sum[0][c] + s_sum[1][c]);
    }
    __syncthreads();

    // out = pooled @ w1 + b1 (threads 0..127 only; small)
    if (t < 128) {
        float acc = b1[c];
#pragma unroll 4
        for (int d = 0; d < DP; ++d)
            acc = fmaf(s_pool[0][d], w1[(size_t)d * DP + c], acc);
        out[(size_t)bn * DP + c] = acc;
    }
}

// ---------------------------------------------------------------------------
// Kernel 2: disf path.
// One block per (b,n). 256 threads.
//   dgf = [pg(3) | pf(64) | dg(1) | df(1)]  with
//     pg = g - gn, pf = f - fn, dg = ||g-2gn||, df = ||f-2fn||
//   disf[k][c] = sum_d dgf[k][d] * w2[d][c] + b2[c]
// Phase A: wave w builds rows k = w*8..w*8+7 of s_dgf (lane d handles pf[d]).
// Phase B: thread t owns col c=t&127, rows kh*16..kh*16+15; w2 column in regs.
// ---------------------------------------------------------------------------
__global__ __launch_bounds__(256) void disf_kernel(
    const float* __restrict__ g,    // [B,N,C]
    const float* __restrict__ f,    // [B,N,D]
    const float* __restrict__ gn,   // [B,N,K,C]
    const float* __restrict__ fn,   // [B,N,K,D]
    const float* __restrict__ w2,   // [DC,DP]
    const float* __restrict__ b2,   // [DP]
    float* __restrict__ disf)       // [B,N,K,DP]
{
    __shared__ float s_dgf[Kv][72];  // 69 used, stride 72 keeps f4 alignment

    const int bn   = blockIdx.x;
    const int t    = threadIdx.x;
    const int lane = t & 63;
    const int w    = t >> 6;

    // Phase A
    {
        const float fv = f[(size_t)bn * Dv + lane];          // lane = d (0..63)
        const float g0 = g[(size_t)bn * Cv + 0];
        const float g1 = g[(size_t)bn * Cv + 1];
        const float g2 = g[(size_t)bn * Cv + 2];
#pragma unroll
        for (int r = 0; r < 8; ++r) {
            const int k = w * 8 + r;
            const float fnv = fn[((size_t)bn * Kv + k) * Dv + lane];
            const float pf  = fv - fnv;
            s_dgf[k][3 + lane] = pf;
            const float q  = pf - fnv;  // f - 2fn
            float sq = q * q;
#pragma unroll
            for (int o = 32; o; o >>= 1) sq += __shfl_xor(sq, o);
            if (lane == 0) {
                const float gn0 = gn[((size_t)bn * Kv + k) * Cv + 0];
                const float gn1 = gn[((size_t)bn * Kv + k) * Cv + 1];
                const float gn2 = gn[((size_t)bn * Kv + k) * Cv + 2];
                const float p0 = g0 - gn0, p1 = g1 - gn1, p2 = g2 - gn2;
                s_dgf[k][0] = p0;
                s_dgf[k][1] = p1;
                s_dgf[k][2] = p2;
                const float q0 = p0 - gn0, q1 = p1 - gn1, q2 = p2 - gn2;
                s_dgf[k][67] = sqrtf(q0 * q0 + q1 * q1 + q2 * q2);
                s_dgf[k][68] = sqrtf(sq);
            }
        }
    }
    __syncthreads();

    // Phase B
    const int c  = t & 127;
    const int kh = t >> 7;

    float w2c[DC];
#pragma unroll
    for (int d = 0; d < DC; ++d) w2c[d] = w2[(size_t)d * DP + c];
    const float b2v = b2[c];

#pragma unroll
    for (int i = 0; i < 16; ++i) {
        const int k = kh * 16 + i;
        const float4* row = (const float4*)(&s_dgf[k][0]);
        float sum = 0.f;
#pragma unroll
        for (int j = 0; j < 17; ++j) {   // d = 0..67
            float4 v = row[j];
            sum = fmaf(v.x, w2c[4 * j + 0], sum);
            sum = fmaf(v.y, w2c[4 * j + 1], sum);
            sum = fmaf(v.z, w2c[4 * j + 2], sum);
            sum = fmaf(v.w, w2c[4 * j + 3], sum);
        }
        sum = fmaf(s_dgf[k][68], w2c[68], sum);  // d = 68
        disf[(((size_t)bn * Kv + k) * DP) + c] = sum + b2v;
    }
}

extern "C" void kernel_launch(void* const* d_in, const int* in_sizes, int n_in,
                              void* d_out, int out_size, void* d_ws, size_t ws_size,
                              hipStream_t stream) {
    (void)in_sizes; (void)n_in; (void)d_ws; (void)ws_size; (void)out_size;

    const float* g   = (const float*)d_in[0];
    const float* f   = (const float*)d_in[1];
    const float* gn  = (const float*)d_in[2];
    const float* fn  = (const float*)d_in[3];
    const float* nfn = (const float*)d_in[4];
    const float* a   = (const float*)d_in[5];
    const float* w2  = (const float*)d_in[6];
    const float* b2  = (const float*)d_in[7];
    const float* w1  = (const float*)d_in[8];
    const float* b1  = (const float*)d_in[9];

    float* out  = (float*)d_out;                       // [B,N,DP]
    float* disf = out + (size_t)Bv * Nv * DP;          // [B,N,K,DP]

    dim3 grid(Bv * Nv);
    dim3 block(256);
    attn_kernel<<<grid, block, 0, stream>>>(nfn, a, w1, b1, out);
    disf_kernel<<<grid, block, 0, stream>>>(g, f, gn, fn, w2, b2, disf);
}

// Round 4
// 802.510 us; speedup vs baseline: 1.3588x; 1.3588x over previous
//
#include <hip/hip_runtime.h>
#include <math.h>

// Problem dims (fixed by the reference)
constexpr int Bv = 4;
constexpr int Nv = 4096;
constexpr int Kv = 32;    // nsample
constexpr int Cv = 3;     // xyz
constexpr int Dv = 64;    // feat
constexpr int DP = 128;   // all_channel
constexpr float ALPHA = 0.2f;

typedef __bf16 bf16x8 __attribute__((ext_vector_type(8)));
typedef float  f32x4  __attribute__((ext_vector_type(4)));
typedef short  s16x8  __attribute__((ext_vector_type(8)));

__device__ __forceinline__ short f2bf(float x) {
    unsigned u = __float_as_uint(x);
    unsigned r = (u + 0x7FFFu + ((u >> 16) & 1u)) >> 16;
    return (short)r;
}
__device__ __forceinline__ float bf2f(short s) {
    return __uint_as_float(((unsigned)(unsigned short)s) << 16);
}
// swizzled LDS byte offset for a [rows][128 bf16] tile (256 B row stride)
__device__ __forceinline__ int swz(int row, int bytecol) {
    return row * 256 + (bytecol ^ ((row & 7) << 4));
}
__device__ __forceinline__ bf16x8 ld_frag(const char* base, int row, int bytecol) {
    return __builtin_bit_cast(bf16x8, *(const s16x8*)(base + swz(row, bytecol)));
}

// ---------------------------------------------------------------------------
// prep: build bf16 pre-swizzled aT / w2T (permuted+padded) and fp32 w1T in ws
// ws layout: [0:32KB) aT_swz  [32KB:64KB) w2T_swz  [64KB:128KB) w1T fp32
// dgf slot permutation: slot s<64 -> pf d=s (orig row 3+s); 64..66 -> pg (0..2);
//                       67 -> dg (orig 67); 68 -> df (orig 68); 69..127 -> 0
// ---------------------------------------------------------------------------
__global__ __launch_bounds__(256) void prep_kernel(
    const float* __restrict__ a, const float* __restrict__ w2,
    const float* __restrict__ w1,
    short* __restrict__ aT_swz, short* __restrict__ w2T_swz,
    float* __restrict__ w1T)
{
    const int idx = blockIdx.x * 256 + threadIdx.x;  // 0..16383
    const int c = idx >> 7, s = idx & 127;
    const int off = (c * 256 + ((s * 2) ^ ((c & 7) << 4))) >> 1;
    aT_swz[off] = f2bf(a[(size_t)s * DP + c]);
    float v = 0.f;
    if (s < 64)       v = w2[(size_t)(3 + s) * DP + c];
    else if (s < 67)  v = w2[(size_t)(s - 64) * DP + c];
    else if (s == 67) v = w2[(size_t)67 * DP + c];
    else if (s == 68) v = w2[(size_t)68 * DP + c];
    w2T_swz[off] = f2bf(v);
    w1T[(size_t)c * DP + s] = w1[(size_t)s * DP + c];
}

// ---------------------------------------------------------------------------
// attn: per block 128 rows (= 4 (b,n) groups x 32 k) of e = nfn @ a,
// leaky-relu, softmax over k, pool, then out = pooled @ w1 + b1.
// 4 waves in 2x2 grid of 64x64 output tiles; K=128 (4 MFMA k-steps).
// ---------------------------------------------------------------------------
__global__ __launch_bounds__(256, 2) void attn_kernel(
    const float* __restrict__ nfn,   // [B*N*K, 128]
    const short* __restrict__ aT_swz,
    const float* __restrict__ w1T,   // [c][d] fp32
    const float* __restrict__ b1,
    float* __restrict__ out)         // [B*N, 128]
{
    __shared__ __align__(16) char s_nfn[128 * 256];  // bf16 [row][128], swizzled
    __shared__ __align__(16) char s_aT[128 * 256];   // bf16 aT[c][k], swizzled
    __shared__ float s_pool[4][DP];

    const int bn0 = blockIdx.x * 4;
    const int t = threadIdx.x;

    // stage aT (already bf16+swizzled in ws): linear copy
    {
        const s16x8* src = (const s16x8*)aT_swz;
        s16x8* dst = (s16x8*)s_aT;
#pragma unroll
        for (int i = 0; i < 8; ++i) dst[t + 256 * i] = src[t + 256 * i];
    }
    // stage nfn rows -> bf16 swizzled. thread: row r = t>>1, half h = t&1
    {
        const int r = t >> 1, h = t & 1;
        const float4* src = (const float4*)(nfn + ((size_t)bn0 * 32 + r) * DP + h * 64);
#pragma unroll
        for (int cc = 0; cc < 8; ++cc) {
            float4 v0 = src[2 * cc], v1 = src[2 * cc + 1];
            s16x8 v = { f2bf(v0.x), f2bf(v0.y), f2bf(v0.z), f2bf(v0.w),
                        f2bf(v1.x), f2bf(v1.y), f2bf(v1.z), f2bf(v1.w) };
            *(s16x8*)(s_nfn + swz(r, h * 128 + cc * 16)) = v;
        }
    }
    __syncthreads();

    const int w = t >> 6, lane = t & 63;
    const int wr = w >> 1, wc = w & 1;
    const int lg = lane >> 4, lm = lane & 15;

    f32x4 acc[4][4];
#pragma unroll
    for (int mt = 0; mt < 4; ++mt)
#pragma unroll
        for (int nt = 0; nt < 4; ++nt) acc[mt][nt] = (f32x4)0.f;

#pragma unroll
    for (int kt = 0; kt < 4; ++kt) {
        bf16x8 afr[4], bfr[4];
#pragma unroll
        for (int mt = 0; mt < 4; ++mt)
            afr[mt] = ld_frag(s_nfn, wr * 64 + mt * 16 + lm, kt * 64 + lg * 16);
#pragma unroll
        for (int nt = 0; nt < 4; ++nt)
            bfr[nt] = ld_frag(s_aT, wc * 64 + nt * 16 + lm, kt * 64 + lg * 16);
#pragma unroll
        for (int mt = 0; mt < 4; ++mt)
#pragma unroll
            for (int nt = 0; nt < 4; ++nt)
                acc[mt][nt] = __builtin_amdgcn_mfma_f32_16x16x32_bf16(
                    afr[mt], bfr[nt], acc[mt][nt], 0, 0, 0);
    }

    // leaky-relu + softmax over 32-row groups + pooled (att * nfn)
#pragma unroll
    for (int gp = 0; gp < 2; ++gp) {          // group within wave rows
#pragma unroll
        for (int nt = 0; nt < 4; ++nt) {
            float v[8];
            float m = -1e30f;
#pragma unroll
            for (int tt = 0; tt < 2; ++tt)
#pragma unroll
                for (int rg = 0; rg < 4; ++rg) {
                    float e = acc[2 * gp + tt][nt][rg];
                    e = e > 0.f ? e : ALPHA * e;
                    v[tt * 4 + rg] = e;
                    m = fmaxf(m, e);
                }
            m = fmaxf(m, __shfl_xor(m, 16));
            m = fmaxf(m, __shfl_xor(m, 32));
            float s = 0.f, p = 0.f;
            const int col = wc * 64 + nt * 16 + lm;
#pragma unroll
            for (int tt = 0; tt < 2; ++tt)
#pragma unroll
                for (int rg = 0; rg < 4; ++rg) {
                    float ex = __expf(v[tt * 4 + rg] - m);
                    s += ex;
                    const int row = wr * 64 + (2 * gp + tt) * 16 + lg * 4 + rg;
                    p += ex * bf2f(*(const short*)(s_nfn + swz(row, col * 2)));
                }
            s += __shfl_xor(s, 16); s += __shfl_xor(s, 32);
            p += __shfl_xor(p, 16); p += __shfl_xor(p, 32);
            if (lg == 0) s_pool[wr * 2 + gp][col] = p / s;
        }
    }
    __syncthreads();

    // out[4][128] = pooled @ w1 + b1  (w1T rows are contiguous)
    {
        const int c = t & 127, g2 = t >> 7;
        const float4* w1r = (const float4*)(w1T + (size_t)c * DP);
#pragma unroll
        for (int gg = 0; gg < 2; ++gg) {
            const int g = g2 + 2 * gg;
            const float4* pr = (const float4*)(&s_pool[g][0]);
            float acc2 = b1[c];
#pragma unroll
            for (int j = 0; j < 32; ++j) {
                float4 wv = w1r[j];
                float4 pv = pr[j];
                acc2 = fmaf(pv.x, wv.x, acc2);
                acc2 = fmaf(pv.y, wv.y, acc2);
                acc2 = fmaf(pv.z, wv.z, acc2);
                acc2 = fmaf(pv.w, wv.w, acc2);
            }
            out[((size_t)bn0 + g) * DP + c] = acc2;
        }
    }
}

// ---------------------------------------------------------------------------
// disf: per block 128 rows of dgf (permuted slots, bf16, swizzled LDS),
// GEMM [128][96] @ w2T -> [128][128], +b2, fp32 store.
// ---------------------------------------------------------------------------
__global__ __launch_bounds__(256, 2) void disf_kernel(
    const float* __restrict__ g,    // [B*N, 3]
    const float* __restrict__ f,    // [B*N, 64]
    const float* __restrict__ gn,   // [B*N*K, 3]
    const float* __restrict__ fn,   // [B*N*K, 64]
    const short* __restrict__ w2T_swz,
    const float* __restrict__ b2,
    float* __restrict__ disf)       // [B*N*K, 128]
{
    __shared__ __align__(16) char s_dgf[128 * 256];
    __shared__ __align__(16) char s_w2T[128 * 256];

    const int bn0 = blockIdx.x * 4;
    const int t = threadIdx.x;

    // stage w2T (pre-swizzled bf16)
    {
        const s16x8* src = (const s16x8*)w2T_swz;
        s16x8* dst = (s16x8*)s_w2T;
#pragma unroll
        for (int i = 0; i < 8; ++i) dst[t + 256 * i] = src[t + 256 * i];
    }
    // build dgf rows: thread r = t>>1, h = t&1 handles pf dims h*32..h*32+31
    {
        const int r = t >> 1, h = t & 1;
        const int grp = r >> 5, k = r & 31;
        const size_t bn = bn0 + grp;
        const float4* fp  = (const float4*)(f + bn * Dv + h * 32);
        const float4* fnp = (const float4*)(fn + (bn * Kv + k) * Dv + h * 32);
        float sq = 0.f;
#pragma unroll
        for (int cc = 0; cc < 4; ++cc) {
            float4 f0 = fp[2 * cc],  f1 = fp[2 * cc + 1];
            float4 n0 = fnp[2 * cc], n1 = fnp[2 * cc + 1];
            float p0 = f0.x - n0.x, p1 = f0.y - n0.y, p2 = f0.z - n0.z, p3 = f0.w - n0.w;
            float p4 = f1.x - n1.x, p5 = f1.y - n1.y, p6 = f1.z - n1.z, p7 = f1.w - n1.w;
            float q;
            q = p0 - n0.x; sq += q * q;  q = p1 - n0.y; sq += q * q;
            q = p2 - n0.z; sq += q * q;  q = p3 - n0.w; sq += q * q;
            q = p4 - n1.x; sq += q * q;  q = p5 - n1.y; sq += q * q;
            q = p6 - n1.z; sq += q * q;  q = p7 - n1.w; sq += q * q;
            s16x8 v = { f2bf(p0), f2bf(p1), f2bf(p2), f2bf(p3),
                        f2bf(p4), f2bf(p5), f2bf(p6), f2bf(p7) };
            *(s16x8*)(s_dgf + swz(r, h * 64 + cc * 16)) = v;
        }
        sq += __shfl_xor(sq, 1);   // combine the two halves of the row
        if (h == 0) {
            const float* gp  = g + bn * Cv;
            const float* gnp = gn + (bn * Kv + k) * Cv;
            float p0 = gp[0] - gnp[0], p1 = gp[1] - gnp[1], p2 = gp[2] - gnp[2];
            float q0 = p0 - gnp[0], q1 = p1 - gnp[1], q2 = p2 - gnp[2];
            float dg = sqrtf(q0 * q0 + q1 * q1 + q2 * q2);
            float df = sqrtf(sq);
            s16x8 z = (s16x8)(short)0;
            s16x8 head = z;
            head[0] = f2bf(p0); head[1] = f2bf(p1); head[2] = f2bf(p2);
            head[3] = f2bf(dg); head[4] = f2bf(df);
            *(s16x8*)(s_dgf + swz(r, 128)) = head;      // slots 64..71
            *(s16x8*)(s_dgf + swz(r, 144)) = z;         // 72..79
            *(s16x8*)(s_dgf + swz(r, 160)) = z;         // 80..87
            *(s16x8*)(s_dgf + swz(r, 176)) = z;         // 88..95
        }
    }
    __syncthreads();

    const int w = t >> 6, lane = t & 63;
    const int wr = w >> 1, wc = w & 1;
    const int lg = lane >> 4, lm = lane & 15;

    f32x4 acc[4][4];
#pragma unroll
    for (int mt = 0; mt < 4; ++mt)
#pragma unroll
        for (int nt = 0; nt < 4; ++nt) acc[mt][nt] = (f32x4)0.f;

#pragma unroll
    for (int kt = 0; kt < 3; ++kt) {        // K = 96
        bf16x8 afr[4], bfr[4];
#pragma unroll
        for (int mt = 0; mt < 4; ++mt)
            afr[mt] = ld_frag(s_dgf, wr * 64 + mt * 16 + lm, kt * 64 + lg * 16);
#pragma unroll
        for (int nt = 0; nt < 4; ++nt)
            bfr[nt] = ld_frag(s_w2T, wc * 64 + nt * 16 + lm, kt * 64 + lg * 16);
#pragma unroll
        for (int mt = 0; mt < 4; ++mt)
#pragma unroll
            for (int nt = 0; nt < 4; ++nt)
                acc[mt][nt] = __builtin_amdgcn_mfma_f32_16x16x32_bf16(
                    afr[mt], bfr[nt], acc[mt][nt], 0, 0, 0);
    }

    float b2v[4];
#pragma unroll
    for (int nt = 0; nt < 4; ++nt) b2v[nt] = b2[wc * 64 + nt * 16 + lm];

#pragma unroll
    for (int mt = 0; mt < 4; ++mt) {
#pragma unroll
        for (int rg = 0; rg < 4; ++rg) {
            const int row = wr * 64 + mt * 16 + lg * 4 + rg;
            float* dst = disf + ((size_t)bn0 * 32 + row) * DP + wc * 64 + lm;
#pragma unroll
            for (int nt = 0; nt < 4; ++nt)
                dst[nt * 16] = acc[mt][nt][rg] + b2v[nt];
        }
    }
}

extern "C" void kernel_launch(void* const* d_in, const int* in_sizes, int n_in,
                              void* d_out, int out_size, void* d_ws, size_t ws_size,
                              hipStream_t stream) {
    (void)in_sizes; (void)n_in; (void)out_size; (void)ws_size;

    const float* g   = (const float*)d_in[0];
    const float* f   = (const float*)d_in[1];
    const float* gn  = (const float*)d_in[2];
    const float* fn  = (const float*)d_in[3];
    const float* nfn = (const float*)d_in[4];
    const float* a   = (const float*)d_in[5];
    const float* w2  = (const float*)d_in[6];
    const float* b2  = (const float*)d_in[7];
    const float* w1  = (const float*)d_in[8];
    const float* b1  = (const float*)d_in[9];

    float* out  = (float*)d_out;                   // [B,N,DP]
    float* disf = out + (size_t)Bv * Nv * DP;      // [B,N,K,DP]

    short* aT_swz  = (short*)d_ws;                 // 32 KB
    short* w2T_swz = aT_swz + 128 * 128;           // 32 KB
    float* w1T     = (float*)(w2T_swz + 128 * 128);// 64 KB

    prep_kernel<<<64, 256, 0, stream>>>(a, w2, w1, aT_swz, w2T_swz, w1T);

    dim3 grid(Bv * Nv / 4);
    attn_kernel<<<grid, 256, 0, stream>>>(nfn, aT_swz, w1T, b1, out);
    disf_kernel<<<grid, 256, 0, stream>>>(g, f, gn, fn, w2T_swz, b2, disf);
}

// Round 6
// 705.851 us; speedup vs baseline: 1.5449x; 1.1369x over previous
//
#include <hip/hip_runtime.h>
#include <math.h>

// Problem dims (fixed by the reference)
constexpr int Bv = 4;
constexpr int Nv = 4096;
constexpr int Kv = 32;    // nsample
constexpr int Cv = 3;     // xyz
constexpr int Dv = 64;    // feat
constexpr int DP = 128;   // all_channel
constexpr float ALPHA = 0.2f;
constexpr int NG = Bv * Nv;   // 16384 (b,n) groups

typedef __bf16 bf16x8 __attribute__((ext_vector_type(8)));
typedef float  f32x16 __attribute__((ext_vector_type(16)));
typedef short  s16x8  __attribute__((ext_vector_type(8)));
typedef short  s16x4  __attribute__((ext_vector_type(4)));

__device__ __forceinline__ short f2bf(float x) {
    unsigned u = __float_as_uint(x);
    unsigned r = (u + 0x7FFFu + ((u >> 16) & 1u)) >> 16;
    return (short)r;
}
__device__ __forceinline__ float bf2f(short s) {
    return __uint_as_float(((unsigned)(unsigned short)s) << 16);
}
// swizzled LDS byte offset for a [rows][128 bf16] tile (256 B row stride)
__device__ __forceinline__ int swz(int row, int bytecol) {
    return row * 256 + (bytecol ^ ((row & 7) << 4));
}
__device__ __forceinline__ bf16x8 ld_frag(const char* base, int row, int bytecol) {
    return __builtin_bit_cast(bf16x8, *(const s16x8*)(base + swz(row, bytecol)));
}

// ---------------------------------------------------------------------------
// prep: bf16 pre-swizzled aT / w2T (permuted+padded) / w1T in ws.
// aT[c][d]=a[d][c]; w1T[c][d]=w1[d][c];
// w2T slot permutation: s<64 -> pf (orig 3+s); 64..66 -> pg; 67 -> dg; 68 -> df.
// ---------------------------------------------------------------------------
__global__ __launch_bounds__(256) void prep_kernel(
    const float* __restrict__ a, const float* __restrict__ w2,
    const float* __restrict__ w1,
    short* __restrict__ aT_swz, short* __restrict__ w2T_swz,
    short* __restrict__ w1T_swz)
{
    const int idx = blockIdx.x * 256 + threadIdx.x;  // 0..16383
    const int c = idx >> 7, s = idx & 127;
    const int off = (c * 256 + ((s * 2) ^ ((c & 7) << 4))) >> 1;
    aT_swz[off]  = f2bf(a[(size_t)s * DP + c]);
    w1T_swz[off] = f2bf(w1[(size_t)s * DP + c]);
    float v = 0.f;
    if (s < 64)       v = w2[(size_t)(3 + s) * DP + c];
    else if (s < 67)  v = w2[(size_t)(s - 64) * DP + c];
    else if (s == 67) v = w2[(size_t)67 * DP + c];
    else if (s == 68) v = w2[(size_t)68 * DP + c];
    w2T_swz[off] = f2bf(v);
}

// ---------------------------------------------------------------------------
// attn_core: wave-independent. Each wave loops over 4 (b,n) groups.
// Per group: stage nfn (32x128) bf16 into wave-private LDS, 32x32x16 MFMA
// e = nfn@a (C rows = k, cols = c), lane-local softmax over k
// (16 regs + one shfl_xor(32)), pooled -> scratch.
// ---------------------------------------------------------------------------
__global__ __launch_bounds__(256, 2) void attn_core(
    const float* __restrict__ nfn,   // [NG*32, 128]
    const short* __restrict__ aT_swz,
    float* __restrict__ pooled)      // [NG, 128]
{
    __shared__ __align__(16) char s_aT[128 * 256];
    __shared__ __align__(16) char s_buf[4][32 * 256];

    const int t = threadIdx.x, w = t >> 6, l = t & 63;
    const int lg = l >> 5, lG = l & 31;

    {   // stage aT once per block
        const s16x8* src = (const s16x8*)aT_swz;
        s16x8* dst = (s16x8*)s_aT;
#pragma unroll
        for (int i = 0; i < 8; ++i) dst[t + 256 * i] = src[t + 256 * i];
    }
    __syncthreads();          // only block-wide barrier

    char* buf = s_buf[w];
    const int g0 = blockIdx.x * 16 + w * 4;

    float4 rv[16];
    {   // prologue: coalesced load of group g0 (16 KB tile, 1 KB/inst)
        const float4* src = (const float4*)(nfn + (size_t)g0 * Kv * DP);
#pragma unroll
        for (int j = 0; j < 16; ++j) rv[j] = src[j * 64 + l];
    }

    for (int it = 0; it < 4; ++it) {
        const int g = g0 + it;
        // write staged tile: rv[j] holds floats of row 2j+lg, col 4*lG
#pragma unroll
        for (int j = 0; j < 16; ++j) {
            s16x4 v = { f2bf(rv[j].x), f2bf(rv[j].y), f2bf(rv[j].z), f2bf(rv[j].w) };
            *(s16x4*)(buf + swz(j * 2 + lg, lG * 8)) = v;
        }
        if (it < 3) {  // prefetch next group's tile under this group's compute
            const float4* src = (const float4*)(nfn + (size_t)(g + 1) * Kv * DP);
#pragma unroll
            for (int j = 0; j < 16; ++j) rv[j] = src[j * 64 + l];
        }

        bf16x8 afr[8];
#pragma unroll
        for (int k = 0; k < 8; ++k) afr[k] = ld_frag(buf, lG, k * 32 + lg * 16);

        f32x16 acc[4];
#pragma unroll
        for (int nt = 0; nt < 4; ++nt) acc[nt] = (f32x16)0.f;
#pragma unroll
        for (int k = 0; k < 8; ++k)
#pragma unroll
            for (int nt = 0; nt < 4; ++nt) {
                bf16x8 bfr = ld_frag(s_aT, nt * 32 + lG, k * 32 + lg * 16);
                acc[nt] = __builtin_amdgcn_mfma_f32_32x32x16_bf16(
                    afr[k], bfr, acc[nt], 0, 0, 0);
            }

        // lane-local softmax over the 32 k's of column c = nt*32+lG
#pragma unroll
        for (int nt = 0; nt < 4; ++nt) {
            float v[16];
            float m = -1e30f;
#pragma unroll
            for (int r = 0; r < 16; ++r) {
                float e = acc[nt][r];
                e = e > 0.f ? e : ALPHA * e;
                v[r] = e;
                m = fmaxf(m, e);
            }
            m = fmaxf(m, __shfl_xor(m, 32));
            float s = 0.f, p = 0.f;
            const int col = nt * 32 + lG;
#pragma unroll
            for (int r = 0; r < 16; ++r) {
                float ex = __expf(v[r] - m);
                s += ex;
                const int row = (r & 3) + 8 * (r >> 2) + 4 * lg;
                p += ex * bf2f(*(const short*)(buf + swz(row, col * 2)));
            }
            s += __shfl_xor(s, 32);
            p += __shfl_xor(p, 32);
            if (lg == 0) pooled[(size_t)g * DP + col] = p / s;
        }
    }
}

// ---------------------------------------------------------------------------
// out_proj: out = pooled @ w1 + b1.  [16384][128]@[128][128], 512 groups of
// 32 rows; 128 blocks x 4 waves x 1 group. Same structure minus softmax.
// ---------------------------------------------------------------------------
__global__ __launch_bounds__(256, 2) void out_proj(
    const float* __restrict__ pooled, const short* __restrict__ w1T_swz,
    const float* __restrict__ b1, float* __restrict__ out)
{
    __shared__ __align__(16) char s_w1[128 * 256];
    __shared__ __align__(16) char s_buf[4][32 * 256];

    const int t = threadIdx.x, w = t >> 6, l = t & 63;
    const int lg = l >> 5, lG = l & 31;
    {
        const s16x8* src = (const s16x8*)w1T_swz;
        s16x8* dst = (s16x8*)s_w1;
#pragma unroll
        for (int i = 0; i < 8; ++i) dst[t + 256 * i] = src[t + 256 * i];
    }
    __syncthreads();

    char* buf = s_buf[w];
    const int grp = blockIdx.x * 4 + w;   // 0..511
    {
        const float4* src = (const float4*)(pooled + (size_t)grp * 32 * DP);
#pragma unroll
        for (int j = 0; j < 16; ++j) {
            float4 v4 = src[j * 64 + l];
            s16x4 v = { f2bf(v4.x), f2bf(v4.y), f2bf(v4.z), f2bf(v4.w) };
            *(s16x4*)(buf + swz(j * 2 + lg, lG * 8)) = v;
        }
    }
    bf16x8 afr[8];
#pragma unroll
    for (int k = 0; k < 8; ++k) afr[k] = ld_frag(buf, lG, k * 32 + lg * 16);

    f32x16 acc[4];
#pragma unroll
    for (int nt = 0; nt < 4; ++nt) acc[nt] = (f32x16)0.f;
#pragma unroll
    for (int k = 0; k < 8; ++k)
#pragma unroll
        for (int nt = 0; nt < 4; ++nt) {
            bf16x8 bfr = ld_frag(s_w1, nt * 32 + lG, k * 32 + lg * 16);
            acc[nt] = __builtin_amdgcn_mfma_f32_32x32x16_bf16(
                afr[k], bfr, acc[nt], 0, 0, 0);
        }
    float b1v[4];
#pragma unroll
    for (int nt = 0; nt < 4; ++nt) b1v[nt] = b1[nt * 32 + lG];
#pragma unroll
    for (int nt = 0; nt < 4; ++nt)
#pragma unroll
        for (int r = 0; r < 16; ++r) {
            const int row = (r & 3) + 8 * (r >> 2) + 4 * lg;
            out[((size_t)grp * 32 + row) * DP + nt * 32 + lG] = acc[nt][r] + b1v[nt];
        }
}

// ---------------------------------------------------------------------------
// disf: wave-independent. Per group: build dgf (32 rows, permuted slots,
// K=96 live) in wave-private LDS, 32x32x16 MFMA vs w2T, +b2, fp32 store.
// ---------------------------------------------------------------------------
__global__ __launch_bounds__(256, 2) void disf_kernel(
    const float* __restrict__ g,    // [NG, 3]
    const float* __restrict__ f,    // [NG, 64]
    const float* __restrict__ gn,   // [NG*32, 3]
    const float* __restrict__ fn,   // [NG*32, 64]
    const short* __restrict__ w2T_swz,
    const float* __restrict__ b2,
    float* __restrict__ disf)       // [NG*32, 128]
{
    __shared__ __align__(16) char s_w2[128 * 256];
    __shared__ __align__(16) char s_buf[4][32 * 256];

    const int t = threadIdx.x, w = t >> 6, l = t & 63;
    const int lg = l >> 5, lG = l & 31;
    {
        const s16x8* src = (const s16x8*)w2T_swz;
        s16x8* dst = (s16x8*)s_w2;
#pragma unroll
        for (int i = 0; i < 8; ++i) dst[t + 256 * i] = src[t + 256 * i];
    }
    __syncthreads();

    char* buf = s_buf[w];
    const int g0 = blockIdx.x * 16 + w * 4;

    float b2v[4];
#pragma unroll
    for (int nt = 0; nt < 4; ++nt) b2v[nt] = b2[nt * 32 + lG];

    // prologue loads for group g0: lane -> row k=lG, d-half lg
    float4 rf[8], rn[8];
    float gv0, gv1, gv2, gn0, gn1, gn2;
    {
        const float4* fp  = (const float4*)(f + (size_t)g0 * Dv + lg * 32);
        const float4* fnp = (const float4*)(fn + ((size_t)g0 * Kv + lG) * Dv + lg * 32);
#pragma unroll
        for (int j = 0; j < 8; ++j) { rf[j] = fp[j]; rn[j] = fnp[j]; }
        const float* gp  = g + (size_t)g0 * Cv;
        const float* gnp = gn + ((size_t)g0 * Kv + lG) * Cv;
        gv0 = gp[0]; gv1 = gp[1]; gv2 = gp[2];
        gn0 = gnp[0]; gn1 = gnp[1]; gn2 = gnp[2];
    }

    for (int it = 0; it < 4; ++it) {
        const int bn = g0 + it;
        // pf + df partial
        float sq = 0.f;
#pragma unroll
        for (int j = 0; j < 4; ++j) {
            float4 a0 = rf[2 * j], a1 = rf[2 * j + 1];
            float4 n0 = rn[2 * j], n1 = rn[2 * j + 1];
            float p0 = a0.x - n0.x, p1 = a0.y - n0.y, p2 = a0.z - n0.z, p3 = a0.w - n0.w;
            float p4 = a1.x - n1.x, p5 = a1.y - n1.y, p6 = a1.z - n1.z, p7 = a1.w - n1.w;
            float q;
            q = p0 - n0.x; sq += q * q;  q = p1 - n0.y; sq += q * q;
            q = p2 - n0.z; sq += q * q;  q = p3 - n0.w; sq += q * q;
            q = p4 - n1.x; sq += q * q;  q = p5 - n1.y; sq += q * q;
            q = p6 - n1.z; sq += q * q;  q = p7 - n1.w; sq += q * q;
            s16x8 v = { f2bf(p0), f2bf(p1), f2bf(p2), f2bf(p3),
                        f2bf(p4), f2bf(p5), f2bf(p6), f2bf(p7) };
            *(s16x8*)(buf + swz(lG, lg * 64 + j * 16)) = v;
        }
        sq += __shfl_xor(sq, 32);   // combine the two d-halves of row lG
        if (lg == 0) {
            float p0 = gv0 - gn0, p1 = gv1 - gn1, p2 = gv2 - gn2;
            float q0 = p0 - gn0, q1 = p1 - gn1, q2 = p2 - gn2;
            float dg = sqrtf(q0 * q0 + q1 * q1 + q2 * q2);
            float df = sqrtf(sq);
            s16x8 z = (s16x8)(short)0;
            s16x8 head = z;
            head[0] = f2bf(p0); head[1] = f2bf(p1); head[2] = f2bf(p2);
            head[3] = f2bf(dg); head[4] = f2bf(df);
            *(s16x8*)(buf + swz(lG, 128)) = head;   // slots 64..71
            *(s16x8*)(buf + swz(lG, 144)) = z;      // 72..79
            *(s16x8*)(buf + swz(lG, 160)) = z;      // 80..87
            *(s16x8*)(buf + swz(lG, 176)) = z;      // 88..95
        }
        if (it < 3) {  // prefetch next group
            const float4* fp  = (const float4*)(f + (size_t)(bn + 1) * Dv + lg * 32);
            const float4* fnp = (const float4*)(fn + ((size_t)(bn + 1) * Kv + lG) * Dv + lg * 32);
#pragma unroll
            for (int j = 0; j < 8; ++j) { rf[j] = fp[j]; rn[j] = fnp[j]; }
            const float* gp  = g + (size_t)(bn + 1) * Cv;
            const float* gnp = gn + ((size_t)(bn + 1) * Kv + lG) * Cv;
            gv0 = gp[0]; gv1 = gp[1]; gv2 = gp[2];
            gn0 = gnp[0]; gn1 = gnp[1]; gn2 = gnp[2];
        }

        bf16x8 afr[6];
#pragma unroll
        for (int k = 0; k < 6; ++k) afr[k] = ld_frag(buf, lG, k * 32 + lg * 16);

        f32x16 acc[4];
#pragma unroll
        for (int nt = 0; nt < 4; ++nt) acc[nt] = (f32x16)0.f;
#pragma unroll
        for (int k = 0; k < 6; ++k)
#pragma unroll
            for (int nt = 0; nt < 4; ++nt) {
                bf16x8 bfr = ld_frag(s_w2, nt * 32 + lG, k * 32 + lg * 16);
                acc[nt] = __builtin_amdgcn_mfma_f32_32x32x16_bf16(
                    afr[k], bfr, acc[nt], 0, 0, 0);
            }
#pragma unroll
        for (int nt = 0; nt < 4; ++nt)
#pragma unroll
            for (int r = 0; r < 16; ++r) {
                const int row = (r & 3) + 8 * (r >> 2) + 4 * lg;
                disf[((size_t)bn * Kv + row) * DP + nt * 32 + lG] = acc[nt][r] + b2v[nt];
            }
    }
}

extern "C" void kernel_launch(void* const* d_in, const int* in_sizes, int n_in,
                              void* d_out, int out_size, void* d_ws, size_t ws_size,
                              hipStream_t stream) {
    (void)in_sizes; (void)n_in; (void)out_size; (void)ws_size;

    const float* g   = (const float*)d_in[0];
    const float* f   = (const float*)d_in[1];
    const float* gn  = (const float*)d_in[2];
    const float* fn  = (const float*)d_in[3];
    const float* nfn = (const float*)d_in[4];
    const float* a   = (const float*)d_in[5];
    const float* w2  = (const float*)d_in[6];
    const float* b2  = (const float*)d_in[7];
    const float* w1  = (const float*)d_in[8];
    const float* b1  = (const float*)d_in[9];

    float* out  = (float*)d_out;                   // [NG, 128]
    float* disf = out + (size_t)NG * DP;           // [NG*32, 128]
    // scratch for pooled: tail of disf region (overwritten by disf_kernel later)
    float* pooled = disf + (size_t)NG * Kv * DP - (size_t)NG * DP;

    short* aT_swz  = (short*)d_ws;                 // 32 KB
    short* w2T_swz = aT_swz + 128 * 128;           // 32 KB
    short* w1T_swz = w2T_swz + 128 * 128;          // 32 KB

    prep_kernel<<<64, 256, 0, stream>>>(a, w2, w1, aT_swz, w2T_swz, w1T_swz);
    attn_core<<<1024, 256, 0, stream>>>(nfn, aT_swz, pooled);
    out_proj<<<128, 256, 0, stream>>>(pooled, w1T_swz, b1, out);
    disf_kernel<<<1024, 256, 0, stream>>>(g, f, gn, fn, w2T_swz, b2, disf);
}